// Round 13
// baseline (134.295 us; speedup 1.0000x reference)
//
#include <hip/hip_runtime.h>
#include <hip/hip_bf16.h>

typedef unsigned short ushort_t;
typedef unsigned int uint_t;
typedef __attribute__((ext_vector_type(8))) short s16x8;
typedef __attribute__((ext_vector_type(4))) float f32x4;
typedef __attribute__((ext_vector_type(4))) ushort_t u16x4;
typedef __attribute__((ext_vector_type(8))) ushort_t u16x8;

__device__ __forceinline__ ushort_t f2bf(float f) {
    uint_t u = __float_as_uint(f);
    uint_t r = (u + 0x7FFFu + ((u >> 16) & 1u)) >> 16;
    return (ushort_t)r;
}
__device__ __forceinline__ float bf2f(ushort_t u) {
    return __uint_as_float(((uint_t)u) << 16);
}
__device__ __forceinline__ s16x8 relu8(s16x8 v) {
    s16x8 r;
#pragma unroll
    for (int e = 0; e < 8; ++e) { short xv = v[e]; r[e] = (xv < 0) ? (short)0 : xv; }
    return r;
}

// ---- prep_all: [0,1024) xtr tiles; [1024,1752) misc; block 1024 also zeroes flags ----
__global__ __launch_bounds__(256) void prep_all(const float* __restrict__ x,
                                                const float* __restrict__ p1,
                                                const float* __restrict__ p10,
                                                const float* __restrict__ p7,
                                                ushort_t* __restrict__ t1h,
                                                ushort_t* __restrict__ xpTh,
                                                ushort_t* __restrict__ wfc,
                                                ushort_t* __restrict__ p7h,
                                                uint_t* __restrict__ flags) {
    __shared__ float xs[64][65];
    __shared__ float p1s[64];
    const int b = blockIdx.x;
    const int t = threadIdx.x;
    if (b < 1024) {
        const int y  = b & 63;
        const int c0 = ((b >> 6) & 1) * 64;
        const int n  = b >> 7;
        if (t < 64) p1s[t] = p1[(c0 + t) * 64 + y];
#pragma unroll
        for (int cc = 0; cc < 4; ++cc) {
            int c = cc * 16 + (t >> 4);
            int px = (t & 15) * 4;
            float4 v = *(const float4*)(x + ((size_t)((n * 128 + c0 + c)) * 64 + y) * 64 + px);
            xs[c][px] = v.x; xs[c][px + 1] = v.y; xs[c][px + 2] = v.z; xs[c][px + 3] = v.w;
        }
        __syncthreads();
        {
            int c = t >> 2, px0 = (t & 3) * 16;
            float pv = p1s[c];
            u16x8 o0, o1;
#pragma unroll
            for (int e = 0; e < 8; ++e) {
                o0[e] = f2bf(pv * xs[c][px0 + e]);
                o1[e] = f2bf(pv * xs[c][px0 + 8 + e]);
            }
            ushort_t* dst = t1h + (size_t)(n * 128 + c0 + c) * 4096 + y * 64 + px0;
            *(u16x8*)dst = o0;
            *(u16x8*)(dst + 8) = o1;
        }
        {
            int p = t >> 2, cx0 = (t & 3) * 16;
            u16x8 r0, r1;
#pragma unroll
            for (int e = 0; e < 8; ++e) {
                r0[e] = f2bf(xs[cx0 + e][p]);
                r1[e] = f2bf(xs[cx0 + 8 + e][p]);
            }
            size_t baseP = ((size_t)n * 4752 + (y + 1) * 72 + p + 3) * 128 + c0 + cx0;
            *(u16x8*)(xpTh + baseP) = r0;
            *(u16x8*)(xpTh + baseP + 8) = r1;
        }
    } else {
        if (b == 1024 && t < 16) flags[t] = 0u;
        int idx = (b - 1024) * 256 + t;         // < 186368
        if (idx < 83968) {
            int chunk = idx & 15;
            int rest  = idx >> 4;               // n*656 + s
            int n = rest / 656;
            int s = rest - n * 656;
            int yy, xx;
            if (s < 144) { yy = (s < 72) ? 0 : 65; xx = s % 72; }
            else { int s2 = s - 144; yy = (s2 >> 3) + 1; int k = s2 & 7; xx = (k < 3) ? k : k + 64; }
            u16x8 z = {};
            *(u16x8*)(xpTh + ((size_t)n * 4752 + yy * 72 + xx) * 128 + chunk * 8) = z;
        } else if (idx < 83968 + 86016) {
            int i = idx - 83968;
            int c32 = i & 31;
            int j = (i >> 5) & 31;
            int rest = i >> 10;                 // g*21 + tap
            int tap = rest % 21, g = rest / 21;
            wfc[i] = f2bf(p10[((32 * g + c32) * 21 + tap) * 32 + j]);
        } else if (idx < 83968 + 86016 + 16384) {
            int i = idx - 83968 - 86016;
            p7h[i] = f2bf(p7[i]);
        }
    }
}

// ---- mega: guf (b -> pt,g,n_g) + last-block ureduce + flag + outf (b -> y,n_o) ----
__global__ __launch_bounds__(256, 2) void mega_mfma(const ushort_t* __restrict__ xpTh,
                                                    const ushort_t* __restrict__ wfc,
                                                    const ushort_t* __restrict__ t1h,
                                                    const ushort_t* __restrict__ p7h,
                                                    const float* __restrict__ p1,
                                                    ushort_t* __restrict__ uparth,
                                                    ushort_t* __restrict__ Uh,
                                                    uint_t* __restrict__ flags,
                                                    float* __restrict__ out) {
    __shared__ __align__(16) char smem[53248];
    __shared__ uint_t sflag;
    uint_t* cnt  = flags;       // [8]
    uint_t* done = flags + 8;   // [8]
    const int b = blockIdx.x;
    const int tid = threadIdx.x;
    const int lane = tid & 63, wid = tid >> 6;
    const int q = lane >> 4, fr = lane & 15;

    // ================= guf phase: (pt, g, n_g) =================
    {
        ushort_t* Ts = (ushort_t*)smem;                 // 27,648 B
        ushort_t* Gs = (ushort_t*)(smem + 27648);       // 16,384 B
        const int n_g = b & 7;
        const int g   = (b >> 3) & 3;
        const int pt  = b >> 5;
        const int p0  = pt * 256;
        const int y0  = p0 >> 6;

        const ushort_t* src = xpTh + ((size_t)n_g * 4752 + y0 * 72) * 128 + g * 32;
        for (int flat = tid; flat < 1728; flat += 256) {
            int qq = flat & 3;
            int cc = (flat >> 2) % 72;
            int rr = (flat >> 2) / 72;
            u16x8 v = *(const u16x8*)(src + ((size_t)rr * 72 + cc) * 128 + qq * 8);
            *(u16x8*)&Ts[(rr * 72 + cc) * 32 + ((qq ^ ((cc >> 1) & 3)) * 8)] = v;
        }
        __syncthreads();

        const ushort_t* wbase = wfc + (size_t)g * 21 * 1024 + fr * 32 + q * 8;
        f32x4 acc[2][4] = {};
        for (int tap = 0; tap < 21; ++tap) {
            const int ki = tap / 7, kj = tap - ki * 7;
            s16x8 a[2], bb[4];
#pragma unroll
            for (int i = 0; i < 2; ++i)
                a[i] = *(const s16x8*)(wbase + tap * 1024 + i * 16 * 32);
#pragma unroll
            for (int jj = 0; jj < 4; ++jj) {
                int col = wid * 64 + jj * 16 + fr;
                int rr = (col >> 6) + ki;
                int cc = (col & 63) + kj;
                bb[jj] = *(const s16x8*)&Ts[(rr * 72 + cc) * 32 + ((q ^ ((cc >> 1) & 3)) * 8)];
            }
#pragma unroll
            for (int i = 0; i < 2; ++i)
#pragma unroll
                for (int jj = 0; jj < 4; ++jj)
                    acc[i][jj] = __builtin_amdgcn_mfma_f32_16x16x32_bf16(a[i], bb[jj], acc[i][jj], 0, 0, 0);
        }
        // prefetch first phase-2 t1h fragments
        const ushort_t* t1base = t1h + (size_t)n_g * 128 * 4096 + p0;
        const int cb = wid * 32;
        s16x8 bpre[2][2];
#pragma unroll
        for (int kk = 0; kk < 2; ++kk)
#pragma unroll
            for (int l = 0; l < 2; ++l)
                bpre[kk][l] = *(const s16x8*)(t1base + (size_t)(cb + l * 16 + fr) * 4096 + kk * 32 + q * 8);

#pragma unroll
        for (int i = 0; i < 2; ++i) {
#pragma unroll
            for (int jj = 0; jj < 4; ++jj) {
                int p = wid * 64 + jj * 16 + fr;
                int pc = p >> 3, pe = p & 7;
#pragma unroll
                for (int reg = 0; reg < 4; ++reg) {
                    int j = i * 16 + q * 4 + reg;
                    Gs[j * 256 + ((pc ^ (j & 7)) * 8) + pe] = f2bf(acc[i][jj][reg]);
                }
            }
        }
        __syncthreads();

        f32x4 accu[2][2] = {};
        for (int kk = 0; kk < 8; ++kk) {
            s16x8 a[2], bb[2];
#pragma unroll
            for (int i = 0; i < 2; ++i) {
                int j = i * 16 + fr;
                a[i] = *(const s16x8*)&Gs[j * 256 + (((kk * 4 + q) ^ (j & 7)) * 8)];
            }
            if (kk < 2) {
#pragma unroll
                for (int l = 0; l < 2; ++l) bb[l] = bpre[kk][l];
            } else {
#pragma unroll
                for (int l = 0; l < 2; ++l)
                    bb[l] = *(const s16x8*)(t1base + (size_t)(cb + l * 16 + fr) * 4096 + kk * 32 + q * 8);
            }
#pragma unroll
            for (int i = 0; i < 2; ++i)
#pragma unroll
                for (int l = 0; l < 2; ++l)
                    accu[i][l] = __builtin_amdgcn_mfma_f32_16x16x32_bf16(a[i], bb[l], accu[i][l], 0, 0, 0);
        }
#pragma unroll
        for (int i = 0; i < 2; ++i) {
#pragma unroll
            for (int l = 0; l < 2; ++l) {
                int c = cb + l * 16 + fr;
                u16x4 o;
#pragma unroll
                for (int reg = 0; reg < 4; ++reg) o[reg] = f2bf(accu[i][l][reg]);
                *(u16x4*)&uparth[((size_t)(n_g * 16 + pt) * 128 + c) * 128 + g * 32 + i * 16 + q * 4] = o;
            }
        }
        __syncthreads();                         // drains global stores (vmcnt) per wave
        if (tid == 0) {
            __threadfence();
            uint_t old = __hip_atomic_fetch_add(&cnt[n_g], 1u, __ATOMIC_ACQ_REL, __HIP_MEMORY_SCOPE_AGENT);
            sflag = (old == 63u) ? 1u : 0u;
        }
        __syncthreads();
        if (sflag) {                             // last block for n_g: reduce Uh[n_g]
            for (int i = tid; i < 4096; i += 256) {
                int rc4 = i * 4;
                float s0 = 0, s1 = 0, s2 = 0, s3 = 0;
#pragma unroll
                for (int k = 0; k < 16; ++k) {
                    u16x4 v = *(const u16x4*)&uparth[(size_t)((n_g * 16 + k) << 14) + rc4];
                    s0 += bf2f(v[0]); s1 += bf2f(v[1]); s2 += bf2f(v[2]); s3 += bf2f(v[3]);
                }
                u16x4 o;
                o[0] = f2bf(s0 * 0.015625f); o[1] = f2bf(s1 * 0.015625f);
                o[2] = f2bf(s2 * 0.015625f); o[3] = f2bf(s3 * 0.015625f);
                *(u16x4*)&Uh[n_g * 16384 + rc4] = o;
            }
            __syncthreads();
            if (tid == 0) {
                __threadfence();
                __hip_atomic_store(&done[n_g], 1u, __ATOMIC_RELEASE, __HIP_MEMORY_SCOPE_AGENT);
            }
        }
    }

    // ================= outf phase: (y, n_o) =================
    const int n_o = b >> 6;
    const int y   = b & 63;
    if (tid == 0) {
        while (__hip_atomic_load(&done[n_o], __ATOMIC_ACQUIRE, __HIP_MEMORY_SCOPE_AGENT) == 0u)
            __builtin_amdgcn_s_sleep(8);
    }
    __syncthreads();
    {
        ushort_t* Bs   = (ushort_t*)smem;                       // 16,384 B
        ushort_t* Cs   = (ushort_t*)(smem + 16384);             // 19,968 B
        ushort_t* T12s = (ushort_t*)(smem + 36352);             // 16,384 B
        float*    p1s  = (float*)(smem + 52736);                // 512 B
        const int w = wid;

        if (tid < 128) p1s[tid] = p1[tid * 64 + y];
        int adS[4], chS[4];
#pragma unroll
        for (int it = 0; it < 4; ++it) {
            int slot = it * 256 + tid;
            int row = slot >> 4, ch = slot & 15;
            chS[it] = ch;
            adS[it] = (row * 16 + (ch ^ (row & 15))) * 8;
            u16x8 v = *(const u16x8*)(xpTh + ((size_t)n_o * 4752 + (y + 1) * 72 + 3 + row) * 128 + ch * 8);
            *(u16x8*)&Bs[adS[it]] = v;
        }
        __syncthreads();

        f32x4 acc[2][4] = {};
        for (int ks = 0; ks < 4; ++ks) {
            s16x8 a[2], bb[4];
#pragma unroll
            for (int i = 0; i < 2; ++i)
                a[i] = *(const s16x8*)(p7h + (w * 32 + i * 16 + fr) * 128 + ks * 32 + q * 8);
#pragma unroll
            for (int jj = 0; jj < 4; ++jj) {
                int rb = jj * 16 + fr;
                bb[jj] = relu8(*(const s16x8*)&Bs[(rb * 16 + ((ks * 4 + q) ^ (rb & 15))) * 8]);
            }
#pragma unroll
            for (int i = 0; i < 2; ++i)
#pragma unroll
                for (int jj = 0; jj < 4; ++jj)
                    acc[i][jj] = __builtin_amdgcn_mfma_f32_16x16x32_bf16(a[i], bb[jj], acc[i][jj], 0, 0, 0);
        }
        // prefetch Uh fragments; latency hides under epilogue phases
        s16x8 upre[2][4];
#pragma unroll
        for (int i = 0; i < 2; ++i)
#pragma unroll
            for (int ks = 0; ks < 4; ++ks)
                upre[i][ks] = *(const s16x8*)(Uh + ((size_t)(n_o * 128 + w * 32 + i * 16 + fr)) * 128 + ks * 32 + q * 8);

        for (int i2 = tid; i2 < 4992; i2 += 256) ((uint_t*)Cs)[i2] = 0u;
        __syncthreads();
#pragma unroll
        for (int i = 0; i < 2; ++i)
#pragma unroll
            for (int jj = 0; jj < 4; ++jj) {
                int col = jj * 16 + fr;
#pragma unroll
                for (int reg = 0; reg < 4; ++reg) {
                    int row = w * 32 + i * 16 + q * 4 + reg;
                    Cs[row * 78 + 6 + col] = f2bf(acc[i][jj][reg]);
                }
            }
        __syncthreads();
        for (int rep = 0; rep < 32; ++rep) {
            int flat = rep * 256 + tid;
            int c = flat >> 6, xx = flat & 63;
            float s = 0.0f;
#pragma unroll
            for (int jj = 0; jj < 5; ++jj)
                s += bf2f(Cs[c * 78 + xx + 3 * jj]);
            float xv = bf2f(Bs[(xx * 16 + ((c >> 3) ^ (xx & 15))) * 8 + (c & 7)]);
            T12s[flat] = f2bf(xv - 0.2f * s);
        }
        __syncthreads();
#pragma unroll
        for (int it = 0; it < 4; ++it) {
            u16x8 v = *(u16x8*)&Bs[adS[it]];
            u16x8 o;
#pragma unroll
            for (int e = 0; e < 8; ++e)
                o[e] = f2bf(bf2f(v[e]) * (1.0f + p1s[chS[it] * 8 + e]));
            *(u16x8*)&Bs[adS[it]] = o;
        }
        __syncthreads();
        f32x4 acc2[2][4] = {};
        for (int ks = 0; ks < 4; ++ks) {
            s16x8 bb[4];
#pragma unroll
            for (int jj = 0; jj < 4; ++jj) {
                int rb = jj * 16 + fr;
                bb[jj] = *(const s16x8*)&Bs[(rb * 16 + ((ks * 4 + q) ^ (rb & 15))) * 8];
            }
#pragma unroll
            for (int i = 0; i < 2; ++i)
#pragma unroll
                for (int jj = 0; jj < 4; ++jj)
                    acc2[i][jj] = __builtin_amdgcn_mfma_f32_16x16x32_bf16(upre[i][ks], bb[jj], acc2[i][jj], 0, 0, 0);
        }
        const float scale = 0.0192879257f;   // 1/sqrt(2688)
#pragma unroll
        for (int i = 0; i < 2; ++i)
#pragma unroll
            for (int jj = 0; jj < 4; ++jj) {
                int col = jj * 16 + fr;
#pragma unroll
                for (int reg = 0; reg < 4; ++reg) {
                    int row = w * 32 + i * 16 + q * 4 + reg;
                    size_t oi = ((size_t)(n_o * 128 + row)) * 4096 + y * 64 + col;
                    out[oi] = fmaxf(bf2f(T12s[row * 64 + col]), acc2[i][jj][reg] * scale);
                }
            }
    }
}

extern "C" void kernel_launch(void* const* d_in, const int* in_sizes, int n_in,
                              void* d_out, int out_size, void* d_ws, size_t ws_size,
                              hipStream_t stream) {
    const float* x   = (const float*)d_in[0];
    const float* p1  = (const float*)d_in[1];
    const float* p7  = (const float*)d_in[2];
    const float* p10 = (const float*)d_in[3];
    float* out = (float*)d_out;

    ushort_t* t1h    = (ushort_t*)d_ws;         // 4,194,304
    ushort_t* xpTh   = t1h + 4194304;           // 4,866,048
    ushort_t* p7h    = xpTh + 4866048;          // 16,384
    ushort_t* wfc    = p7h + 16384;             // 86,016
    ushort_t* Uh     = wfc + 86016;             // 131,072
    ushort_t* uparth = Uh + 131072;             // 2,097,152
    uint_t*   flags  = (uint_t*)(uparth + 2097152);  // 16 uints (cnt[8] | done[8])

    prep_all<<<1752, 256, 0, stream>>>(x, p1, p10, p7, t1h, xpTh, wfc, p7h, flags);
    mega_mfma<<<512, 256, 0, stream>>>(xpTh, wfc, t1h, p7h, p1, uparth, Uh, flags, out);
}

// Round 14
// 83.319 us; speedup vs baseline: 1.6118x; 1.6118x over previous
//
#include <hip/hip_runtime.h>
#include <hip/hip_bf16.h>

typedef unsigned short ushort_t;
typedef unsigned int uint_t;
typedef __attribute__((ext_vector_type(8))) short s16x8;
typedef __attribute__((ext_vector_type(4))) float f32x4;
typedef __attribute__((ext_vector_type(4))) ushort_t u16x4;
typedef __attribute__((ext_vector_type(8))) ushort_t u16x8;

__device__ __forceinline__ ushort_t f2bf(float f) {
    uint_t u = __float_as_uint(f);
    uint_t r = (u + 0x7FFFu + ((u >> 16) & 1u)) >> 16;
    return (ushort_t)r;
}
__device__ __forceinline__ float bf2f(ushort_t u) {
    return __uint_as_float(((uint_t)u) << 16);
}
__device__ __forceinline__ s16x8 relu8(s16x8 v) {
    s16x8 r;
#pragma unroll
    for (int e = 0; e < 8; ++e) { short xv = v[e]; r[e] = (xv < 0) ? (short)0 : xv; }
    return r;
}

// ---- prep_all: [0,1024) xtr tiles; [1024,1752) misc; block 1024 zeroes cnt ----
__global__ __launch_bounds__(256) void prep_all(const float* __restrict__ x,
                                                const float* __restrict__ p1,
                                                const float* __restrict__ p10,
                                                const float* __restrict__ p7,
                                                ushort_t* __restrict__ t1h,
                                                ushort_t* __restrict__ xpTh,
                                                ushort_t* __restrict__ wfc,
                                                ushort_t* __restrict__ p7h,
                                                uint_t* __restrict__ flags) {
    __shared__ float xs[64][65];
    __shared__ float p1s[64];
    const int b = blockIdx.x;
    const int t = threadIdx.x;
    if (b < 1024) {
        const int y  = b & 63;
        const int c0 = ((b >> 6) & 1) * 64;
        const int n  = b >> 7;
        if (t < 64) p1s[t] = p1[(c0 + t) * 64 + y];
#pragma unroll
        for (int cc = 0; cc < 4; ++cc) {
            int c = cc * 16 + (t >> 4);
            int px = (t & 15) * 4;
            float4 v = *(const float4*)(x + ((size_t)((n * 128 + c0 + c)) * 64 + y) * 64 + px);
            xs[c][px] = v.x; xs[c][px + 1] = v.y; xs[c][px + 2] = v.z; xs[c][px + 3] = v.w;
        }
        __syncthreads();
        {
            int c = t >> 2, px0 = (t & 3) * 16;
            float pv = p1s[c];
            u16x8 o0, o1;
#pragma unroll
            for (int e = 0; e < 8; ++e) {
                o0[e] = f2bf(pv * xs[c][px0 + e]);
                o1[e] = f2bf(pv * xs[c][px0 + 8 + e]);
            }
            ushort_t* dst = t1h + (size_t)(n * 128 + c0 + c) * 4096 + y * 64 + px0;
            *(u16x8*)dst = o0;
            *(u16x8*)(dst + 8) = o1;
        }
        {
            int p = t >> 2, cx0 = (t & 3) * 16;
            u16x8 r0, r1;
#pragma unroll
            for (int e = 0; e < 8; ++e) {
                r0[e] = f2bf(xs[cx0 + e][p]);
                r1[e] = f2bf(xs[cx0 + 8 + e][p]);
            }
            size_t baseP = ((size_t)n * 4752 + (y + 1) * 72 + p + 3) * 128 + c0 + cx0;
            *(u16x8*)(xpTh + baseP) = r0;
            *(u16x8*)(xpTh + baseP + 8) = r1;
        }
    } else {
        if (b == 1024 && t < 8) flags[t] = 0u;
        int idx = (b - 1024) * 256 + t;         // < 186368
        if (idx < 83968) {
            int chunk = idx & 15;
            int rest  = idx >> 4;               // n*656 + s
            int n = rest / 656;
            int s = rest - n * 656;
            int yy, xx;
            if (s < 144) { yy = (s < 72) ? 0 : 65; xx = s % 72; }
            else { int s2 = s - 144; yy = (s2 >> 3) + 1; int k = s2 & 7; xx = (k < 3) ? k : k + 64; }
            u16x8 z = {};
            *(u16x8*)(xpTh + ((size_t)n * 4752 + yy * 72 + xx) * 128 + chunk * 8) = z;
        } else if (idx < 83968 + 86016) {
            int i = idx - 83968;
            int c32 = i & 31;
            int j = (i >> 5) & 31;
            int rest = i >> 10;                 // g*21 + tap
            int tap = rest % 21, g = rest / 21;
            wfc[i] = f2bf(p10[((32 * g + c32) * 21 + tap) * 32 + j]);
        } else if (idx < 83968 + 86016 + 16384) {
            int i = idx - 83968 - 86016;
            p7h[i] = f2bf(p7[i]);
        }
    }
}

// ---- fused G-conv + U-partial + last-block-per-n Uh reduction ----
// grid (16 pt, 4 g, 8 n). No waiting: 64th finisher for an n reduces Uh[n].
__global__ __launch_bounds__(256) void guf_mfma(const ushort_t* __restrict__ xpTh,
                                                const ushort_t* __restrict__ wfc,
                                                const ushort_t* __restrict__ t1h,
                                                ushort_t* __restrict__ uparth,
                                                ushort_t* __restrict__ Uh,
                                                uint_t* __restrict__ cnt) {
    __shared__ ushort_t Ts[6 * 72 * 32];
    __shared__ ushort_t Gs[32 * 256];
    __shared__ uint_t sflag;
    const int pt = blockIdx.x;
    const int p0 = pt * 256;
    const int g  = blockIdx.y;
    const int n  = blockIdx.z;
    const int tid = threadIdx.x;
    const int lane = tid & 63, wid = tid >> 6;
    const int q = lane >> 4, fr = lane & 15;
    const int y0 = p0 >> 6;

    const ushort_t* src = xpTh + ((size_t)n * 4752 + y0 * 72) * 128 + g * 32;
    for (int flat = tid; flat < 1728; flat += 256) {
        int qq = flat & 3;
        int cc = (flat >> 2) % 72;
        int rr = (flat >> 2) / 72;
        u16x8 v = *(const u16x8*)(src + ((size_t)rr * 72 + cc) * 128 + qq * 8);
        *(u16x8*)&Ts[(rr * 72 + cc) * 32 + ((qq ^ ((cc >> 1) & 3)) * 8)] = v;
    }
    __syncthreads();

    const ushort_t* wbase = wfc + (size_t)g * 21 * 1024 + fr * 32 + q * 8;
    f32x4 acc[2][4] = {};
    for (int tap = 0; tap < 21; ++tap) {
        const int ki = tap / 7, kj = tap - ki * 7;
        s16x8 a[2], b[4];
#pragma unroll
        for (int i = 0; i < 2; ++i)
            a[i] = *(const s16x8*)(wbase + tap * 1024 + i * 16 * 32);
#pragma unroll
        for (int jj = 0; jj < 4; ++jj) {
            int col = wid * 64 + jj * 16 + fr;
            int rr = (col >> 6) + ki;
            int cc = (col & 63) + kj;
            b[jj] = *(const s16x8*)&Ts[(rr * 72 + cc) * 32 + ((q ^ ((cc >> 1) & 3)) * 8)];
        }
#pragma unroll
        for (int i = 0; i < 2; ++i)
#pragma unroll
            for (int jj = 0; jj < 4; ++jj)
                acc[i][jj] = __builtin_amdgcn_mfma_f32_16x16x32_bf16(a[i], b[jj], acc[i][jj], 0, 0, 0);
    }
    // T14: issue first phase-2 t1h fragments now
    const ushort_t* t1base = t1h + (size_t)n * 128 * 4096 + p0;
    const int cb = wid * 32;
    s16x8 bpre[2][2];
#pragma unroll
    for (int kk = 0; kk < 2; ++kk)
#pragma unroll
        for (int l = 0; l < 2; ++l)
            bpre[kk][l] = *(const s16x8*)(t1base + (size_t)(cb + l * 16 + fr) * 4096 + kk * 32 + q * 8);

#pragma unroll
    for (int i = 0; i < 2; ++i) {
#pragma unroll
        for (int jj = 0; jj < 4; ++jj) {
            int p = wid * 64 + jj * 16 + fr;
            int pc = p >> 3, pe = p & 7;
#pragma unroll
            for (int reg = 0; reg < 4; ++reg) {
                int j = i * 16 + q * 4 + reg;
                Gs[j * 256 + ((pc ^ (j & 7)) * 8) + pe] = f2bf(acc[i][jj][reg]);
            }
        }
    }
    __syncthreads();

    f32x4 accu[2][2] = {};
    for (int kk = 0; kk < 8; ++kk) {
        s16x8 a[2], b[2];
#pragma unroll
        for (int i = 0; i < 2; ++i) {
            int j = i * 16 + fr;
            a[i] = *(const s16x8*)&Gs[j * 256 + (((kk * 4 + q) ^ (j & 7)) * 8)];
        }
        if (kk < 2) {
#pragma unroll
            for (int l = 0; l < 2; ++l) b[l] = bpre[kk][l];
        } else {
#pragma unroll
            for (int l = 0; l < 2; ++l)
                b[l] = *(const s16x8*)(t1base + (size_t)(cb + l * 16 + fr) * 4096 + kk * 32 + q * 8);
        }
#pragma unroll
        for (int i = 0; i < 2; ++i)
#pragma unroll
            for (int l = 0; l < 2; ++l)
                accu[i][l] = __builtin_amdgcn_mfma_f32_16x16x32_bf16(a[i], b[l], accu[i][l], 0, 0, 0);
    }
#pragma unroll
    for (int i = 0; i < 2; ++i) {
#pragma unroll
        for (int l = 0; l < 2; ++l) {
            int c = cb + l * 16 + fr;
            u16x4 o;
#pragma unroll
            for (int reg = 0; reg < 4; ++reg) o[reg] = f2bf(accu[i][l][reg]);
            *(u16x4*)&uparth[((size_t)(n * 16 + pt) * 128 + c) * 128 + g * 32 + i * 16 + q * 4] = o;
        }
    }
    __syncthreads();
    if (tid == 0) {
        __threadfence();
        uint_t old = __hip_atomic_fetch_add(&cnt[n], 1u, __ATOMIC_ACQ_REL, __HIP_MEMORY_SCOPE_AGENT);
        sflag = (old == 63u) ? 1u : 0u;
    }
    __syncthreads();
    if (sflag) {                                 // 64th finisher: reduce Uh[n]
        for (int i = tid; i < 4096; i += 256) {
            int rc4 = i * 4;
            float s0 = 0, s1 = 0, s2 = 0, s3 = 0;
#pragma unroll
            for (int k = 0; k < 16; ++k) {
                u16x4 v = *(const u16x4*)&uparth[(size_t)((n * 16 + k) << 14) + rc4];
                s0 += bf2f(v[0]); s1 += bf2f(v[1]); s2 += bf2f(v[2]); s3 += bf2f(v[3]);
            }
            u16x4 o;
            o[0] = f2bf(s0 * 0.015625f); o[1] = f2bf(s1 * 0.015625f);
            o[2] = f2bf(s2 * 0.015625f); o[3] = f2bf(s3 * 0.015625f);
            *(u16x4*)&Uh[n * 16384 + rc4] = o;
        }
    }
}

// ---- fully fused output: t7 MFMA + t12 + t13 MFMA + max. grid (64 y, 8 n) ----
__global__ __launch_bounds__(256) void outf_mfma(const ushort_t* __restrict__ p7h,
                                                 const ushort_t* __restrict__ xpTh,
                                                 const ushort_t* __restrict__ Uh,
                                                 const float* __restrict__ p1,
                                                 float* __restrict__ out) {
    __shared__ ushort_t Bs[8192];               // 64p x 128c, swz 16 KB
    __shared__ ushort_t Cs[9984];               // 128 x 78 halo  19.9 KB
    __shared__ ushort_t T12s[8192];             // 128c x 64p     16 KB
    __shared__ float p1s[128];
    const int y = blockIdx.x;
    const int n = blockIdx.y;
    const int tid = threadIdx.x;
    const int lane = tid & 63, w = tid >> 6;
    const int q = lane >> 4, fr = lane & 15;

    if (tid < 128) p1s[tid] = p1[tid * 64 + y];
    int adS[4], chS[4];
#pragma unroll
    for (int it = 0; it < 4; ++it) {
        int slot = it * 256 + tid;
        int row = slot >> 4, ch = slot & 15;
        chS[it] = ch;
        adS[it] = (row * 16 + (ch ^ (row & 15))) * 8;
        u16x8 v = *(const u16x8*)(xpTh + ((size_t)n * 4752 + (y + 1) * 72 + 3 + row) * 128 + ch * 8);
        *(u16x8*)&Bs[adS[it]] = v;
    }
    __syncthreads();

    // phase A: t7 = p7h . relu(Bs)
    f32x4 acc[2][4] = {};
    for (int ks = 0; ks < 4; ++ks) {
        s16x8 a[2], b[4];
#pragma unroll
        for (int i = 0; i < 2; ++i)
            a[i] = *(const s16x8*)(p7h + (w * 32 + i * 16 + fr) * 128 + ks * 32 + q * 8);
#pragma unroll
        for (int jj = 0; jj < 4; ++jj) {
            int rb = jj * 16 + fr;
            b[jj] = relu8(*(const s16x8*)&Bs[(rb * 16 + ((ks * 4 + q) ^ (rb & 15))) * 8]);
        }
#pragma unroll
        for (int i = 0; i < 2; ++i)
#pragma unroll
            for (int jj = 0; jj < 4; ++jj)
                acc[i][jj] = __builtin_amdgcn_mfma_f32_16x16x32_bf16(a[i], b[jj], acc[i][jj], 0, 0, 0);
    }
    // T14: issue Uh A-fragment loads now; latency hides under the t12 epilogue phases
    s16x8 upre[2][4];
#pragma unroll
    for (int i = 0; i < 2; ++i)
#pragma unroll
        for (int ks = 0; ks < 4; ++ks)
            upre[i][ks] = *(const s16x8*)(Uh + ((size_t)(n * 128 + w * 32 + i * 16 + fr)) * 128 + ks * 32 + q * 8);

    for (int i2 = tid; i2 < 4992; i2 += 256) ((uint_t*)Cs)[i2] = 0u;
    __syncthreads();
#pragma unroll
    for (int i = 0; i < 2; ++i)
#pragma unroll
        for (int jj = 0; jj < 4; ++jj) {
            int col = jj * 16 + fr;
#pragma unroll
            for (int reg = 0; reg < 4; ++reg) {
                int row = w * 32 + i * 16 + q * 4 + reg;
                Cs[row * 78 + 6 + col] = f2bf(acc[i][jj][reg]);
            }
        }
    __syncthreads();
    for (int rep = 0; rep < 32; ++rep) {
        int flat = rep * 256 + tid;
        int c = flat >> 6, xx = flat & 63;
        float s = 0.0f;
#pragma unroll
        for (int jj = 0; jj < 5; ++jj)
            s += bf2f(Cs[c * 78 + xx + 3 * jj]);
        float xv = bf2f(Bs[(xx * 16 + ((c >> 3) ^ (xx & 15))) * 8 + (c & 7)]);
        T12s[flat] = f2bf(xv - 0.2f * s);
    }
    __syncthreads();
#pragma unroll
    for (int it = 0; it < 4; ++it) {
        u16x8 v = *(u16x8*)&Bs[adS[it]];
        u16x8 o;
#pragma unroll
        for (int e = 0; e < 8; ++e)
            o[e] = f2bf(bf2f(v[e]) * (1.0f + p1s[chS[it] * 8 + e]));
        *(u16x8*)&Bs[adS[it]] = o;
    }
    __syncthreads();
    f32x4 acc2[2][4] = {};
    for (int ks = 0; ks < 4; ++ks) {
        s16x8 b[4];
#pragma unroll
        for (int jj = 0; jj < 4; ++jj) {
            int rb = jj * 16 + fr;
            b[jj] = *(const s16x8*)&Bs[(rb * 16 + ((ks * 4 + q) ^ (rb & 15))) * 8];
        }
#pragma unroll
        for (int i = 0; i < 2; ++i)
#pragma unroll
            for (int jj = 0; jj < 4; ++jj)
                acc2[i][jj] = __builtin_amdgcn_mfma_f32_16x16x32_bf16(upre[i][ks], b[jj], acc2[i][jj], 0, 0, 0);
    }
    const float scale = 0.0192879257f;   // 1/sqrt(2688)
#pragma unroll
    for (int i = 0; i < 2; ++i)
#pragma unroll
        for (int jj = 0; jj < 4; ++jj) {
            int col = jj * 16 + fr;
#pragma unroll
            for (int reg = 0; reg < 4; ++reg) {
                int row = w * 32 + i * 16 + q * 4 + reg;
                size_t oi = ((size_t)(n * 128 + row)) * 4096 + y * 64 + col;
                out[oi] = fmaxf(bf2f(T12s[row * 64 + col]), acc2[i][jj][reg] * scale);
            }
        }
}

extern "C" void kernel_launch(void* const* d_in, const int* in_sizes, int n_in,
                              void* d_out, int out_size, void* d_ws, size_t ws_size,
                              hipStream_t stream) {
    const float* x   = (const float*)d_in[0];
    const float* p1  = (const float*)d_in[1];
    const float* p7  = (const float*)d_in[2];
    const float* p10 = (const float*)d_in[3];
    float* out = (float*)d_out;

    ushort_t* t1h    = (ushort_t*)d_ws;         // 4,194,304
    ushort_t* xpTh   = t1h + 4194304;           // 4,866,048
    ushort_t* p7h    = xpTh + 4866048;          // 16,384
    ushort_t* wfc    = p7h + 16384;             // 86,016
    ushort_t* Uh     = wfc + 86016;             // 131,072
    ushort_t* uparth = Uh + 131072;             // 2,097,152
    uint_t*   flags  = (uint_t*)(uparth + 2097152);  // cnt[8]

    prep_all<<<1752, 256, 0, stream>>>(x, p1, p10, p7, t1h, xpTh, wfc, p7h, flags);
    guf_mfma<<<dim3(16, 4, 8), 256, 0, stream>>>(xpTh, wfc, t1h, uparth, Uh, flags);
    outf_mfma<<<dim3(64, 8), 256, 0, stream>>>(p7h, xpTh, Uh, p1, out);
}

// Round 15
// 43.545 us; speedup vs baseline: 3.0841x; 1.9134x over previous
//
#include <hip/hip_runtime.h>
#include <hip/hip_bf16.h>

typedef unsigned short ushort_t;
typedef unsigned int uint_t;
typedef __attribute__((ext_vector_type(8))) short s16x8;
typedef __attribute__((ext_vector_type(4))) float f32x4;
typedef __attribute__((ext_vector_type(4))) ushort_t u16x4;
typedef __attribute__((ext_vector_type(8))) ushort_t u16x8;

__device__ __forceinline__ ushort_t f2bf(float f) {
    uint_t u = __float_as_uint(f);
    uint_t r = (u + 0x7FFFu + ((u >> 16) & 1u)) >> 16;
    return (ushort_t)r;
}
__device__ __forceinline__ float bf2f(ushort_t u) {
    return __uint_as_float(((uint_t)u) << 16);
}
__device__ __forceinline__ s16x8 relu8(s16x8 v) {
    s16x8 r;
#pragma unroll
    for (int e = 0; e < 8; ++e) { short xv = v[e]; r[e] = (xv < 0) ? (short)0 : xv; }
    return r;
}

// ---- prep_all: [0,1024) xtr tiles (t1h + xpTh interior); [1024,1752) misc ----
__global__ __launch_bounds__(256) void prep_all(const float* __restrict__ x,
                                                const float* __restrict__ p1,
                                                const float* __restrict__ p10,
                                                const float* __restrict__ p7,
                                                ushort_t* __restrict__ t1h,
                                                ushort_t* __restrict__ xpTh,
                                                ushort_t* __restrict__ wfc,
                                                ushort_t* __restrict__ p7h) {
    __shared__ float xs[64][65];
    __shared__ float p1s[64];
    const int b = blockIdx.x;
    const int t = threadIdx.x;
    if (b < 1024) {
        const int y  = b & 63;
        const int c0 = ((b >> 6) & 1) * 64;
        const int n  = b >> 7;
        if (t < 64) p1s[t] = p1[(c0 + t) * 64 + y];
#pragma unroll
        for (int cc = 0; cc < 4; ++cc) {
            int c = cc * 16 + (t >> 4);
            int px = (t & 15) * 4;
            float4 v = *(const float4*)(x + ((size_t)((n * 128 + c0 + c)) * 64 + y) * 64 + px);
            xs[c][px] = v.x; xs[c][px + 1] = v.y; xs[c][px + 2] = v.z; xs[c][px + 3] = v.w;
        }
        __syncthreads();
        {
            int c = t >> 2, px0 = (t & 3) * 16;
            float pv = p1s[c];
            u16x8 o0, o1;
#pragma unroll
            for (int e = 0; e < 8; ++e) {
                o0[e] = f2bf(pv * xs[c][px0 + e]);
                o1[e] = f2bf(pv * xs[c][px0 + 8 + e]);
            }
            ushort_t* dst = t1h + (size_t)(n * 128 + c0 + c) * 4096 + y * 64 + px0;
            *(u16x8*)dst = o0;
            *(u16x8*)(dst + 8) = o1;
        }
        {
            int p = t >> 2, cx0 = (t & 3) * 16;
            u16x8 r0, r1;
#pragma unroll
            for (int e = 0; e < 8; ++e) {
                r0[e] = f2bf(xs[cx0 + e][p]);
                r1[e] = f2bf(xs[cx0 + 8 + e][p]);
            }
            size_t baseP = ((size_t)n * 4752 + (y + 1) * 72 + p + 3) * 128 + c0 + cx0;
            *(u16x8*)(xpTh + baseP) = r0;
            *(u16x8*)(xpTh + baseP + 8) = r1;
        }
    } else {
        int idx = (b - 1024) * 256 + t;         // < 186368
        if (idx < 83968) {
            int chunk = idx & 15;
            int rest  = idx >> 4;               // n*656 + s
            int n = rest / 656;
            int s = rest - n * 656;
            int yy, xx;
            if (s < 144) { yy = (s < 72) ? 0 : 65; xx = s % 72; }
            else { int s2 = s - 144; yy = (s2 >> 3) + 1; int k = s2 & 7; xx = (k < 3) ? k : k + 64; }
            u16x8 z = {};
            *(u16x8*)(xpTh + ((size_t)n * 4752 + yy * 72 + xx) * 128 + chunk * 8) = z;
        } else if (idx < 83968 + 86016) {
            int i = idx - 83968;
            int c32 = i & 31;
            int j = (i >> 5) & 31;
            int rest = i >> 10;                 // g*21 + tap
            int tap = rest % 21, g = rest / 21;
            wfc[i] = f2bf(p10[((32 * g + c32) * 21 + tap) * 32 + j]);
        } else if (idx < 83968 + 86016 + 16384) {
            int i = idx - 83968 - 86016;
            p7h[i] = f2bf(p7[i]);
        }
    }
}

// ---- fused G-conv + U-partial, p-tile=256: grid (16 pt, 4 g, 8 n) ----
// tap loop software-pipelined 1-deep (prefetch tap+1 regs while tap MFMAs run)
__global__ __launch_bounds__(256) void guf_mfma(const ushort_t* __restrict__ xpTh,
                                                const ushort_t* __restrict__ wfc,
                                                const ushort_t* __restrict__ t1h,
                                                ushort_t* __restrict__ uparth) {
    __shared__ ushort_t Ts[6 * 72 * 32];
    __shared__ ushort_t Gs[32 * 256];
    const int pt = blockIdx.x;
    const int p0 = pt * 256;
    const int g  = blockIdx.y;
    const int n  = blockIdx.z;
    const int tid = threadIdx.x;
    const int lane = tid & 63, wid = tid >> 6;
    const int q = lane >> 4, fr = lane & 15;
    const int y0 = p0 >> 6;

    const ushort_t* src = xpTh + ((size_t)n * 4752 + y0 * 72) * 128 + g * 32;
    for (int flat = tid; flat < 1728; flat += 256) {
        int qq = flat & 3;
        int cc = (flat >> 2) % 72;
        int rr = (flat >> 2) / 72;
        u16x8 v = *(const u16x8*)(src + ((size_t)rr * 72 + cc) * 128 + qq * 8);
        *(u16x8*)&Ts[(rr * 72 + cc) * 32 + ((qq ^ ((cc >> 1) & 3)) * 8)] = v;
    }
    __syncthreads();

    // per-thread constant parts of B addressing
    int c6[4], c63[4];
#pragma unroll
    for (int jj = 0; jj < 4; ++jj) {
        int col = wid * 64 + jj * 16 + fr;
        c6[jj] = col >> 6;
        c63[jj] = col & 63;
    }
    const ushort_t* wbase = wfc + (size_t)g * 21 * 1024 + fr * 32 + q * 8;
    f32x4 acc[2][4] = {};
    s16x8 a[2], b[4];
    // load tap 0 (ki=0, kj=0)
#pragma unroll
    for (int i = 0; i < 2; ++i) a[i] = *(const s16x8*)(wbase + i * 16 * 32);
#pragma unroll
    for (int jj = 0; jj < 4; ++jj) {
        int cc = c63[jj];
        b[jj] = *(const s16x8*)&Ts[(c6[jj] * 72 + cc) * 32 + ((q ^ ((cc >> 1) & 3)) * 8)];
    }
    int ki1 = 0, kj1 = 1;                        // decomposition of tap+1
    for (int tap = 0; tap < 21; ++tap) {
        s16x8 an[2], bn[4];
        if (tap < 20) {
#pragma unroll
            for (int i = 0; i < 2; ++i)
                an[i] = *(const s16x8*)(wbase + (tap + 1) * 1024 + i * 16 * 32);
#pragma unroll
            for (int jj = 0; jj < 4; ++jj) {
                int rr = c6[jj] + ki1;
                int cc = c63[jj] + kj1;
                bn[jj] = *(const s16x8*)&Ts[(rr * 72 + cc) * 32 + ((q ^ ((cc >> 1) & 3)) * 8)];
            }
        }
#pragma unroll
        for (int i = 0; i < 2; ++i)
#pragma unroll
            for (int jj = 0; jj < 4; ++jj)
                acc[i][jj] = __builtin_amdgcn_mfma_f32_16x16x32_bf16(a[i], b[jj], acc[i][jj], 0, 0, 0);
        if (tap < 20) {
#pragma unroll
            for (int i = 0; i < 2; ++i) a[i] = an[i];
#pragma unroll
            for (int jj = 0; jj < 4; ++jj) b[jj] = bn[jj];
            if (++kj1 == 7) { kj1 = 0; ++ki1; }
        }
    }
    // T14: issue first phase-2 t1h fragments now
    const ushort_t* t1base = t1h + (size_t)n * 128 * 4096 + p0;
    const int cb = wid * 32;
    s16x8 bpre[2][2];
#pragma unroll
    for (int kk = 0; kk < 2; ++kk)
#pragma unroll
        for (int l = 0; l < 2; ++l)
            bpre[kk][l] = *(const s16x8*)(t1base + (size_t)(cb + l * 16 + fr) * 4096 + kk * 32 + q * 8);

    // G -> Gs (bf16, chunk-swizzled rows): Gs[j*256 + ((p>>3)^(j&7))*8 + (p&7)]
#pragma unroll
    for (int i = 0; i < 2; ++i) {
#pragma unroll
        for (int jj = 0; jj < 4; ++jj) {
            int p = wid * 64 + jj * 16 + fr;
            int pc = p >> 3, pe = p & 7;
#pragma unroll
            for (int reg = 0; reg < 4; ++reg) {
                int j = i * 16 + q * 4 + reg;
                Gs[j * 256 + ((pc ^ (j & 7)) * 8) + pe] = f2bf(acc[i][jj][reg]);
            }
        }
    }
    __syncthreads();

    // phase 2: Upart^T = Gs . t1h^T over this p-tile (K=256)
    f32x4 accu[2][2] = {};
    for (int kk = 0; kk < 8; ++kk) {
        s16x8 av[2], bv[2];
#pragma unroll
        for (int i = 0; i < 2; ++i) {
            int j = i * 16 + fr;
            av[i] = *(const s16x8*)&Gs[j * 256 + (((kk * 4 + q) ^ (j & 7)) * 8)];
        }
        if (kk < 2) {
#pragma unroll
            for (int l = 0; l < 2; ++l) bv[l] = bpre[kk][l];
        } else {
#pragma unroll
            for (int l = 0; l < 2; ++l)
                bv[l] = *(const s16x8*)(t1base + (size_t)(cb + l * 16 + fr) * 4096 + kk * 32 + q * 8);
        }
#pragma unroll
        for (int i = 0; i < 2; ++i)
#pragma unroll
            for (int l = 0; l < 2; ++l)
                accu[i][l] = __builtin_amdgcn_mfma_f32_16x16x32_bf16(av[i], bv[l], accu[i][l], 0, 0, 0);
    }
#pragma unroll
    for (int i = 0; i < 2; ++i) {
#pragma unroll
        for (int l = 0; l < 2; ++l) {
            int c = cb + l * 16 + fr;
            u16x4 o;
#pragma unroll
            for (int reg = 0; reg < 4; ++reg) o[reg] = f2bf(accu[i][l][reg]);
            *(u16x4*)&uparth[((size_t)(n * 16 + pt) * 128 + c) * 128 + g * 32 + i * 16 + q * 4] = o;
        }
    }
}

__global__ void ureduce_kernel(const ushort_t* __restrict__ uparth, ushort_t* __restrict__ Uh) {
    int idx4 = blockIdx.x * 256 + threadIdx.x;   // < 32768
    int n = idx4 >> 12, rc4 = (idx4 & 4095) * 4;
    float s0 = 0, s1 = 0, s2 = 0, s3 = 0;
#pragma unroll
    for (int k = 0; k < 16; ++k) {
        u16x4 v = *(const u16x4*)&uparth[(size_t)((n * 16 + k) << 14) + rc4];
        s0 += bf2f(v[0]); s1 += bf2f(v[1]); s2 += bf2f(v[2]); s3 += bf2f(v[3]);
    }
    u16x4 o;
    o[0] = f2bf(s0 * 0.015625f); o[1] = f2bf(s1 * 0.015625f);
    o[2] = f2bf(s2 * 0.015625f); o[3] = f2bf(s3 * 0.015625f);
    *(u16x4*)&Uh[n * 16384 + rc4] = o;
}

// ---- fully fused output: t7 MFMA + t12 + t13 MFMA + max. grid (64 y, 8 n) ----
__global__ __launch_bounds__(256) void outf_mfma(const ushort_t* __restrict__ p7h,
                                                 const ushort_t* __restrict__ xpTh,
                                                 const ushort_t* __restrict__ Uh,
                                                 const float* __restrict__ p1,
                                                 float* __restrict__ out) {
    __shared__ ushort_t Bs[8192];               // 64p x 128c, swz 16 KB
    __shared__ ushort_t Cs[9984];               // 128 x 78 halo  19.9 KB
    __shared__ ushort_t T12s[8192];             // 128c x 64p     16 KB
    __shared__ float p1s[128];
    const int y = blockIdx.x;
    const int n = blockIdx.y;
    const int tid = threadIdx.x;
    const int lane = tid & 63, w = tid >> 6;
    const int q = lane >> 4, fr = lane & 15;

    if (tid < 128) p1s[tid] = p1[tid * 64 + y];
    int adS[4], chS[4];
#pragma unroll
    for (int it = 0; it < 4; ++it) {
        int slot = it * 256 + tid;
        int row = slot >> 4, ch = slot & 15;
        chS[it] = ch;
        adS[it] = (row * 16 + (ch ^ (row & 15))) * 8;
        u16x8 v = *(const u16x8*)(xpTh + ((size_t)n * 4752 + (y + 1) * 72 + 3 + row) * 128 + ch * 8);
        *(u16x8*)&Bs[adS[it]] = v;
    }
    __syncthreads();

    // phase A: t7 = p7h . relu(Bs)
    f32x4 acc[2][4] = {};
    for (int ks = 0; ks < 4; ++ks) {
        s16x8 a[2], b[4];
#pragma unroll
        for (int i = 0; i < 2; ++i)
            a[i] = *(const s16x8*)(p7h + (w * 32 + i * 16 + fr) * 128 + ks * 32 + q * 8);
#pragma unroll
        for (int jj = 0; jj < 4; ++jj) {
            int rb = jj * 16 + fr;
            b[jj] = relu8(*(const s16x8*)&Bs[(rb * 16 + ((ks * 4 + q) ^ (rb & 15))) * 8]);
        }
#pragma unroll
        for (int i = 0; i < 2; ++i)
#pragma unroll
            for (int jj = 0; jj < 4; ++jj)
                acc[i][jj] = __builtin_amdgcn_mfma_f32_16x16x32_bf16(a[i], b[jj], acc[i][jj], 0, 0, 0);
    }
    // T14: issue Uh A-fragment loads now; latency hides under the t12 epilogue phases
    s16x8 upre[2][4];
#pragma unroll
    for (int i = 0; i < 2; ++i)
#pragma unroll
        for (int ks = 0; ks < 4; ++ks)
            upre[i][ks] = *(const s16x8*)(Uh + ((size_t)(n * 128 + w * 32 + i * 16 + fr)) * 128 + ks * 32 + q * 8);

    for (int i2 = tid; i2 < 4992; i2 += 256) ((uint_t*)Cs)[i2] = 0u;
    __syncthreads();
#pragma unroll
    for (int i = 0; i < 2; ++i)
#pragma unroll
        for (int jj = 0; jj < 4; ++jj) {
            int col = jj * 16 + fr;
#pragma unroll
            for (int reg = 0; reg < 4; ++reg) {
                int row = w * 32 + i * 16 + q * 4 + reg;
                Cs[row * 78 + 6 + col] = f2bf(acc[i][jj][reg]);
            }
        }
    __syncthreads();
    for (int rep = 0; rep < 32; ++rep) {
        int flat = rep * 256 + tid;
        int c = flat >> 6, xx = flat & 63;
        float s = 0.0f;
#pragma unroll
        for (int jj = 0; jj < 5; ++jj)
            s += bf2f(Cs[c * 78 + xx + 3 * jj]);
        float xv = bf2f(Bs[(xx * 16 + ((c >> 3) ^ (xx & 15))) * 8 + (c & 7)]);
        T12s[flat] = f2bf(xv - 0.2f * s);
    }
    __syncthreads();
#pragma unroll
    for (int it = 0; it < 4; ++it) {
        u16x8 v = *(u16x8*)&Bs[adS[it]];
        u16x8 o;
#pragma unroll
        for (int e = 0; e < 8; ++e)
            o[e] = f2bf(bf2f(v[e]) * (1.0f + p1s[chS[it] * 8 + e]));
        *(u16x8*)&Bs[adS[it]] = o;
    }
    __syncthreads();
    f32x4 acc2[2][4] = {};
    for (int ks = 0; ks < 4; ++ks) {
        s16x8 b[4];
#pragma unroll
        for (int jj = 0; jj < 4; ++jj) {
            int rb = jj * 16 + fr;
            b[jj] = *(const s16x8*)&Bs[(rb * 16 + ((ks * 4 + q) ^ (rb & 15))) * 8];
        }
#pragma unroll
        for (int i = 0; i < 2; ++i)
#pragma unroll
            for (int jj = 0; jj < 4; ++jj)
                acc2[i][jj] = __builtin_amdgcn_mfma_f32_16x16x32_bf16(upre[i][ks], b[jj], acc2[i][jj], 0, 0, 0);
    }
    const float scale = 0.0192879257f;   // 1/sqrt(2688)
#pragma unroll
    for (int i = 0; i < 2; ++i)
#pragma unroll
        for (int jj = 0; jj < 4; ++jj) {
            int col = jj * 16 + fr;
#pragma unroll
            for (int reg = 0; reg < 4; ++reg) {
                int row = w * 32 + i * 16 + q * 4 + reg;
                size_t oi = ((size_t)(n * 128 + row)) * 4096 + y * 64 + col;
                out[oi] = fmaxf(bf2f(T12s[row * 64 + col]), acc2[i][jj][reg] * scale);
            }
        }
}

extern "C" void kernel_launch(void* const* d_in, const int* in_sizes, int n_in,
                              void* d_out, int out_size, void* d_ws, size_t ws_size,
                              hipStream_t stream) {
    const float* x   = (const float*)d_in[0];
    const float* p1  = (const float*)d_in[1];
    const float* p7  = (const float*)d_in[2];
    const float* p10 = (const float*)d_in[3];
    float* out = (float*)d_out;

    ushort_t* t1h    = (ushort_t*)d_ws;         // 4,194,304
    ushort_t* xpTh   = t1h + 4194304;           // 4,866,048
    ushort_t* p7h    = xpTh + 4866048;          // 16,384
    ushort_t* wfc    = p7h + 16384;             // 86,016
    ushort_t* Uh     = wfc + 86016;             // 131,072
    ushort_t* uparth = Uh + 131072;             // 2,097,152

    prep_all<<<1752, 256, 0, stream>>>(x, p1, p10, p7, t1h, xpTh, wfc, p7h);
    guf_mfma<<<dim3(16, 4, 8), 256, 0, stream>>>(xpTh, wfc, t1h, uparth);
    ureduce_kernel<<<128, 256, 0, stream>>>(uparth, Uh);
    outf_mfma<<<dim3(64, 8), 256, 0, stream>>>(p7h, xpTh, Uh, p1, out);
}